// Round 2
// baseline (502.360 us; speedup 1.0000x reference)
//
#include <hip/hip_runtime.h>
#include <hip/hip_fp16.h>
#include <cstdint>
#include <cstddef>

#define M_DIM 8192
#define N_DIM 4096
#define K_DIM 4096

typedef int v4i __attribute__((ext_vector_type(4)));

// ---------------------------------------------------------------------------
// Pack kernel: int32 (harness-widened int8) -> int8.
// One int4 (16B) load -> one uint32 (4B) store per thread, fully coalesced
// per instruction (round 1's 64B/thread version ran ~1 TB/s).
// ---------------------------------------------------------------------------
__global__ __launch_bounds__(256) void pack_i32_to_i8(const int* __restrict__ src,
                                                      uint32_t* __restrict__ dst,
                                                      int n4) {
    int i = blockIdx.x * 256 + threadIdx.x;
    if (i >= n4) return;
    int4 a = ((const int4*)src)[i];
    dst[i] = (uint32_t)(a.x & 0xff) | ((uint32_t)(a.y & 0xff) << 8) |
             ((uint32_t)(a.z & 0xff) << 16) | ((uint32_t)a.w << 24);
}

// ---------------------------------------------------------------------------
// async global->LDS, 16B per lane (global_load_lds_dwordx4)
// ---------------------------------------------------------------------------
__device__ __forceinline__ void gload_lds16(const int8_t* g, int8_t* l) {
    __builtin_amdgcn_global_load_lds(
        (const __attribute__((address_space(1))) void*)g,
        (__attribute__((address_space(3))) void*)l, 16, 0, 0);
}

// ---------------------------------------------------------------------------
// GEMM: C[m][n] = sum_k A[m][k]*W[n][k], int32 acc, fused dequant epilogue.
// 128x128 block tile, BK=128, 4 waves (2x2), wave tile 64x64 via 4x4 MFMA
// tiles of mfma_i32_16x16x64_i8.
//
// LDS layout is FRAGMENT-ORDERED: sX[ksub(2)][subtile s(8)][slot l(64)][16B],
// where subtile s covers rows s*16+(l&15), k-chunk (l>>4) of 64-wide k-half
// ksub. Staging lane l fetches exactly the global 16B that fragment-lane l
// consumes, so ds_read_b128 fragment reads are perfectly stride-1
// (zero bank conflicts), and global_load_lds's wave-uniform-base + l*16
// constraint is satisfied. Global staging reads still cover whole 64B lines
// (16 rows x 4 chunks per instruction).
// ---------------------------------------------------------------------------
__global__ __launch_bounds__(256) void gemm_i8_dq(const int8_t* __restrict__ A,
                                                  const int8_t* __restrict__ W,
                                                  const float* __restrict__ sx,
                                                  const float* __restrict__ sw,
                                                  const float* __restrict__ bias,
                                                  float* __restrict__ out) {
    __shared__ int8_t sA[128 * 128];   // 16 KB
    __shared__ int8_t sB[128 * 128];   // 16 KB

    const int t    = threadIdx.x;
    const int lane = t & 63;
    const int w    = t >> 6;          // wave 0..3
    const int wm   = w >> 1;          // 0..1
    const int wn   = w & 1;           // 0..1
    const int bm   = blockIdx.y;      // 0..63
    const int bn   = blockIdx.x;      // 0..31
    const int r16  = lane & 15;       // row within subtile
    const int c16  = lane >> 4;       // 16B k-chunk within 64-wide k-half

    // ---- staging addresses: 8 issues/thread per K-tile (4 A + 4 B) ----
    const int8_t* gA[4]; const int8_t* gB[4];
    int8_t* lA[4]; int8_t* lB[4];
#pragma unroll
    for (int j = 0; j < 4; j++) {
        const int sgrp = j & 1;        // subtile group
        const int ksub = j >> 1;       // which 64-wide k-half
        const int s    = sgrp * 4 + w; // subtile 0..7
        gA[j] = A + (size_t)(bm * 128 + s * 16 + r16) * K_DIM + ksub * 64 + c16 * 16;
        gB[j] = W + (size_t)(bn * 128 + s * 16 + r16) * K_DIM + ksub * 64 + c16 * 16;
        lA[j] = &sA[(ksub * 8 + s) * 1024 + lane * 16];
        lB[j] = &sB[(ksub * 8 + s) * 1024 + lane * 16];
    }

    v4i acc[4][4];
    const v4i vzero = {0, 0, 0, 0};
#pragma unroll
    for (int mi = 0; mi < 4; mi++)
#pragma unroll
        for (int ni = 0; ni < 4; ni++) acc[mi][ni] = vzero;

    for (int kt = 0; kt < K_DIM; kt += 128) {
        __syncthreads();              // previous tile's ds_reads done
#pragma unroll
        for (int j = 0; j < 4; j++) {
            gload_lds16(gA[j] + kt, lA[j]);
            gload_lds16(gB[j] + kt, lB[j]);
        }
        __syncthreads();              // staging complete

#pragma unroll
        for (int kk = 0; kk < 2; kk++) {
            v4i af[4], bf[4];
#pragma unroll
            for (int i = 0; i < 4; i++) {
                af[i] = *(const v4i*)(&sA[(kk * 8 + wm * 4 + i) * 1024 + lane * 16]);
                bf[i] = *(const v4i*)(&sB[(kk * 8 + wn * 4 + i) * 1024 + lane * 16]);
            }
#pragma unroll
            for (int mi = 0; mi < 4; mi++)
#pragma unroll
                for (int ni = 0; ni < 4; ni++)
                    acc[mi][ni] = __builtin_amdgcn_mfma_i32_16x16x64_i8(
                        af[mi], bf[ni], acc[mi][ni], 0, 0, 0);
        }
    }

    // ---- epilogue: C/D 16x16 layout: col = lane&15, row = (lane>>4)*4 + r ----
    const float DIVF = (float)(1.0 / (127.0 * 127.0));
    const int col0 = bn * 128 + wn * 64 + (lane & 15);
    const int row0 = bm * 128 + wm * 64 + (lane >> 4) * 4;

    float swv[4], bv[4];
#pragma unroll
    for (int ni = 0; ni < 4; ni++) {
        swv[ni] = sw[col0 + ni * 16];
        bv[ni]  = bias[col0 + ni * 16];
    }

#pragma unroll
    for (int mi = 0; mi < 4; mi++) {
#pragma unroll
        for (int r = 0; r < 4; r++) {
            const int row = row0 + mi * 16 + r;
            const float xs = sx[row];
#pragma unroll
            for (int ni = 0; ni < 4; ni++) {
                // numpy op order: ((acc_f * DIV) * sx) * sw + bias, no fma
                float v = __fmul_rn((float)acc[mi][ni][r], DIVF);
                v = __fmul_rn(v, xs);
                v = __fmul_rn(v, swv[ni]);
                v = __fadd_rn(v, bv[ni]);
                out[(size_t)row * N_DIM + col0 + ni * 16] = __half2float(__float2half(v));
            }
        }
    }
}

extern "C" void kernel_launch(void* const* d_in, const int* in_sizes, int n_in,
                              void* d_out, int out_size, void* d_ws, size_t ws_size,
                              hipStream_t stream) {
    const int*   x_i32 = (const int*)d_in[0];      // [M,K] int (widened int8)
    const float* sx    = (const float*)d_in[1];    // [M] f32
    const int*   w_i32 = (const int*)d_in[2];      // [N,K] int (widened int8)
    const float* sw    = (const float*)d_in[3];    // [N] f32
    const float* bias  = (const float*)d_in[4];    // [N] f32 (widened fp16)
    float* out = (float*)d_out;                    // [M,N] f32 (widened fp16)

    uint8_t* xb = (uint8_t*)d_ws;                          // 32 MB packed x
    uint8_t* wb = (uint8_t*)d_ws + (size_t)M_DIM * K_DIM;  // 16 MB packed w

    const int nx4 = (M_DIM * K_DIM) / 4;  // 8,388,608
    const int nw4 = (N_DIM * K_DIM) / 4;  // 4,194,304
    pack_i32_to_i8<<<(nx4 + 255) / 256, 256, 0, stream>>>(x_i32, (uint32_t*)xb, nx4);
    pack_i32_to_i8<<<(nw4 + 255) / 256, 256, 0, stream>>>(w_i32, (uint32_t*)wb, nw4);

    dim3 grid(N_DIM / 128, M_DIM / 128);  // (32, 64)
    gemm_i8_dq<<<grid, 256, 0, stream>>>((const int8_t*)xb, (const int8_t*)wb,
                                         sx, sw, bias, out);
}